// Round 10
// baseline (251.645 us; speedup 1.0000x reference)
//
#include <hip/hip_runtime.h>

#define N_TOK 131072
#define TILE 128             // tokens per tile: 4 barriers / 128 tokens
#define NT_MAX 1040          // N_TOK/TILE + 16 tasks worth of padding tiles
#define NBLK 256             // 16 tasks x 16 blocks, XCD-mapped: 2 tasks per XCD

typedef __attribute__((ext_vector_type(8))) short s8v;
typedef __attribute__((ext_vector_type(4))) float f4v;
typedef unsigned short ushort_t;

__device__ __forceinline__ unsigned short f2bf(float x) {
    union { float f; unsigned u; } v; v.f = x;
    unsigned r = v.u + 0x7fffu + ((v.u >> 16) & 1u);   // RNE (prep only)
    return (unsigned short)(r >> 16);
}

// round-half-up pack of two f32 -> packed bf16x2 via v_perm_b32 (3 VALU ops)
__device__ __forceinline__ unsigned pk2(float a, float b) {
    union { float f; unsigned u; } x, y; x.f = a; y.f = b;
    return __byte_perm(x.u + 0x8000u, y.u + 0x8000u, 0x7632);
}

// tanh = 1 - 2/(e^2x+1); e^2x = exp2(x * 2*log2(e)): mul, exp2, add, rcp, fma
__device__ __forceinline__ float tanh_fast(float x) {
    float e = __builtin_amdgcn_exp2f(x * 2.8853900817779268f);
    float r = __builtin_amdgcn_rcpf(e + 1.0f);
    return __builtin_fmaf(-2.0f, r, 1.0f);
}

// ------------------------------------------------- fused prep + hist
__global__ void prep_hist_kernel(const float* __restrict__ W0, const float* __restrict__ W1,
                                 const float* __restrict__ W2,
                                 ushort_t* __restrict__ W0p, ushort_t* __restrict__ W1p,
                                 ushort_t* __restrict__ W2p,
                                 const int* __restrict__ task, int* __restrict__ blockCounts) {
    if (blockIdx.x < 224) {
        int f = blockIdx.x * 256 + threadIdx.x;   // 57344 total fragments
        const float* src; ushort_t* dst; int K, N;
        if (f < 16384)      { src = W0; dst = W0p; K = 128; N = 256; }
        else if (f < 49152) { src = W1; dst = W1p; K = 256; N = 256; f -= 16384; }
        else                { src = W2; dst = W2p; K = 256; N = 64;  f -= 49152; }
        int fpc = (N >> 4) * (K >> 5) * 64;       // fragments per copy
        int c = f / fpc, r = f % fpc;
        int lane = r & 63;
        int kt = (r >> 6) % (K >> 5);
        int ftile = (r >> 6) / (K >> 5);
        int n = ftile * 16 + (lane & 15);
        int kbase = kt * 32 + (lane >> 4) * 8;
        const float* s = src + (size_t)c * K * N + (size_t)kbase * N + n;
        s8v pk;
#pragma unroll
        for (int j = 0; j < 8; j++) pk[j] = (short)f2bf(s[(size_t)j * N]);
        *reinterpret_cast<s8v*>(dst + ((size_t)(c * fpc + r) << 3)) = pk;
    } else {
        __shared__ int cnt[16];
        int t = threadIdx.x;
        int hb = blockIdx.x - 224;
        if (t < 16) cnt[t] = 0;
        __syncthreads();
        int base = hb * 2048 + t;
#pragma unroll
        for (int i = 0; i < 8; i++) atomicAdd(&cnt[task[base + i * 256]], 1);
        __syncthreads();
        if (t < 16) blockCounts[hb * 16 + t] = cnt[t];
    }
}

// ------------------------------------------------- fused scan + scatter
// Exports tbase[17] (tile range per task) for the persistent mlp kernel.
__global__ void sort_kernel(const int* __restrict__ task, const int* __restrict__ blockCounts,
                            int* __restrict__ tbaseG, int* __restrict__ perm) {
    __shared__ int cntLds[1024];
    __shared__ int total[16], pref[16], rank[16];
    __shared__ int tokBase[16], tbase[17];
    int t = threadIdx.x, b = blockIdx.x;
    for (int i = t; i < 1024; i += 256) cntLds[i] = blockCounts[i];
    if (t < 16) rank[t] = 0;
    __syncthreads();
    if (t < 16) {
        int tot = 0, pf = 0;
#pragma unroll
        for (int bb = 0; bb < 64; bb++) {
            int v = cntLds[bb * 16 + t];
            tot += v;
            if (bb < b) pf += v;
        }
        total[t] = tot; pref[t] = pf;
    }
    __syncthreads();
    if (t == 0) {
        int tok = 0, tile = 0;
        for (int k = 0; k < 16; k++) {
            tokBase[k] = tok;
            tbase[k] = tile;
            int ntk = (total[k] + TILE - 1) / TILE;
            tok += ntk * TILE;
            tile += ntk;
        }
        tbase[16] = tile;
    }
    __syncthreads();
    if (b == 0) {
        if (t < 17) tbaseG[t] = tbase[t];
        // fill padding slots with -1 (don't rely on ws poison being >= N_TOK)
        for (int i = t; i < 16 * TILE; i += 256) {
            int k = i >> 7, off = i & (TILE - 1);
            int idx = total[k] + off;
            int lim = ((total[k] + TILE - 1) / TILE) * TILE;
            if (idx < lim) perm[tokBase[k] + idx] = -1;
        }
    }
    int tk[8], my[8];
#pragma unroll
    for (int i = 0; i < 8; i++) {
        int idx = b * 2048 + i * 256 + t;
        tk[i] = task[idx];
        my[i] = atomicAdd(&rank[tk[i]], 1);
    }
#pragma unroll
    for (int i = 0; i < 8; i++) {
        int idx = b * 2048 + i * 256 + t;
        perm[tokBase[tk[i]] + pref[tk[i]] + my[i]] = idx;
    }
}

// ------------------------------------------------- persistent MLP, 128-tok tiles, 4x4 acc
// R9 falsified weight residency/latency/occupancy as the bottleneck (63us
// invariant). Remaining suspects attacked jointly: (a) JIT load-use chains per
// token (halved: 20 chains per 128 tokens, MFMA cluster 16 per chain), (b)
// barrier drains per token (quartered: 4 per 128), (c) operand reads per MFMA
// (0.75 -> 0.5 via 4x4 acc: wave grid = 4 feature-groups x 2 token-groups).
// Gather for tile+16 is issued AFTER the stage barrier so it drains at the
// L0-end barrier under compute (old code drained it immediately: zero hiding).
// LDS: H1 64KB + X/H2 overlay 64KB = 128KB, 1 block/CU. XCD map: 2 tasks/XCD.
__launch_bounds__(512, 2)
__global__ void mlp_kernel(const float* __restrict__ x_in,
                           const int* __restrict__ cmap,
                           const float* __restrict__ b0,
                           const float* __restrict__ b1,
                           const float* __restrict__ b2,
                           const ushort_t* __restrict__ W0p,
                           const ushort_t* __restrict__ W1p,
                           const ushort_t* __restrict__ W2p,
                           const int* __restrict__ tbaseG,
                           const int* __restrict__ perm,
                           float* __restrict__ out) {
    __shared__ __align__(16) ushort_t H1[32768];     // 8 nt * 8 kt * 64 * 8 = 64 KB
    __shared__ __align__(16) ushort_t XH2[32768];    // X: frags [0,32); H2: frags [0,64)

    int p = blockIdx.x;
    int x = p & 7, s = p >> 3;            // xcd (HW: blockIdx%8), slot-on-xcd
    int k = 2 * x + (s >> 4), sub = s & 15;
    int tBeg = tbaseG[k], tEnd = tbaseG[k + 1];
    if (tBeg + sub >= tEnd) return;

    int t = threadIdx.x;
    int c0 = cmap[k], c1 = cmap[16 + k], c2 = cmap[32 + k];

    int w = t >> 6;                 // wave 0..7
    int lane = t & 63;
    int l15 = lane & 15, lq = lane >> 4;
    int fg = w & 3, tg = w >> 2;    // wave grid: 4 feature-groups x 2 token-groups
    int mt2 = w & 3, ntb2 = (w >> 2) * 4;   // layer-2: 1 mt x 4 nt per wave

    const ushort_t* Wc0 = W0p + (size_t)c0 * 32768;
    const ushort_t* Wc1 = W1p + (size_t)c1 * 65536;
    const ushort_t* Wc2 = W2p + (size_t)c2 * 16384;

    // biases, resident
    f4v bv0[4], bv1[4], bv2;
#pragma unroll
    for (int mi = 0; mi < 4; mi++) {
        bv0[mi] = *reinterpret_cast<const f4v*>(b0 + c0 * 256 + (4 * fg + mi) * 16 + lq * 4);
        bv1[mi] = *reinterpret_cast<const f4v*>(b1 + c1 * 256 + (4 * fg + mi) * 16 + lq * 4);
    }
    bv2 = *reinterpret_cast<const f4v*>(b2 + c2 * 64 + mt2 * 16 + lq * 4);

    // ---- X prefetch state: thread owns token r = t>>2, k-range q*32..q*32+31
    int r = t >> 2, q = t & 3;
    const float4* xbase = reinterpret_cast<const float4*>(x_in);
    float4 v[8];
#pragma unroll
    for (int j = 0; j < 8; j++) v[j] = make_float4(0.f, 0.f, 0.f, 0.f);

    int tile = tBeg + sub;
    {
        int ptok = perm[tile * TILE + r];
        if ((unsigned)ptok < (unsigned)N_TOK) {
            const float4* src = xbase + (size_t)ptok * 32 + q * 8;
#pragma unroll
            for (int j = 0; j < 8; j++) v[j] = src[j];
        }
    }

    for (; tile < tEnd; tile += 16) {
        // ---- stage prefetched X into LDS fragment order (frag = nt*4+kt)
        {
            int fbase = ((r >> 4) * 4 + q) * 64;
#pragma unroll
            for (int gq = 0; gq < 4; gq++) {
                uint4 pk;
                pk.x = pk2(v[2 * gq].x, v[2 * gq].y);         pk.y = pk2(v[2 * gq].z, v[2 * gq].w);
                pk.z = pk2(v[2 * gq + 1].x, v[2 * gq + 1].y); pk.w = pk2(v[2 * gq + 1].z, v[2 * gq + 1].w);
                *reinterpret_cast<uint4*>(&XH2[(fbase + (r & 15) + 16 * gq) << 3]) = pk;
            }
        }
        __syncthreads();

        // ---- issue next tile's gather AFTER the barrier: drains at the
        //      L0-end barrier, hidden under L0 compute (not at this one).
        int ntile = tile + 16;
        if (ntile < tEnd) {
            int ptok = perm[ntile * TILE + r];
            float4 a[8];
#pragma unroll
            for (int j = 0; j < 8; j++) a[j] = make_float4(0.f, 0.f, 0.f, 0.f);
            if ((unsigned)ptok < (unsigned)N_TOK) {
                const float4* src = xbase + (size_t)ptok * 32 + q * 8;
#pragma unroll
                for (int j = 0; j < 8; j++) a[j] = src[j];
            }
#pragma unroll
            for (int j = 0; j < 8; j++) v[j] = a[j];
        }

        // ---- Layer 0: H1^T = W0^T X^T. Wave (fg,tg): 4 ftiles x 4 token tiles.
        {
            f4v acc[4][4];
#pragma unroll
            for (int mi = 0; mi < 4; mi++)
#pragma unroll
                for (int ni = 0; ni < 4; ni++)
                    acc[mi][ni] = bv0[mi];
#pragma unroll
            for (int kt = 0; kt < 4; kt++) {
                s8v wa[4], xb[4];
#pragma unroll
                for (int mi = 0; mi < 4; mi++)
                    wa[mi] = *reinterpret_cast<const s8v*>(Wc0 + ((((4 * fg + mi) * 4 + kt) * 64 + lane) << 3));
#pragma unroll
                for (int ni = 0; ni < 4; ni++)
                    xb[ni] = *reinterpret_cast<const s8v*>(&XH2[(((4 * tg + ni) * 4 + kt) * 64 + lane) << 3]);
#pragma unroll
                for (int mi = 0; mi < 4; mi++)
#pragma unroll
                    for (int ni = 0; ni < 4; ni++)
                        acc[mi][ni] = __builtin_amdgcn_mfma_f32_16x16x32_bf16(wa[mi], xb[ni], acc[mi][ni], 0, 0, 0);
            }
#pragma unroll
            for (int mi = 0; mi < 4; mi++) {
                int ft = 4 * fg + mi;
                int kt_h = ft >> 1;
                int lanep = l15 + 16 * ((ft & 1) * 2 + (lq >> 1));
                int j0 = (lq & 1) * 4;
#pragma unroll
                for (int ni = 0; ni < 4; ni++) {
                    int nt = 4 * tg + ni;
                    float t0 = tanh_fast(acc[mi][ni][0]);
                    float t1 = tanh_fast(acc[mi][ni][1]);
                    float t2 = tanh_fast(acc[mi][ni][2]);
                    float t3 = tanh_fast(acc[mi][ni][3]);
                    uint2 pk; pk.x = pk2(t0, t1); pk.y = pk2(t2, t3);
                    *reinterpret_cast<uint2*>(&H1[(((nt * 8 + kt_h) * 64 + lanep) << 3) + j0]) = pk;
                }
            }
        }
        __syncthreads();

        // ---- Layer 1: H2^T = W1^T H1^T. (H2 overlays X region, frags [0,64).)
        {
            f4v acc[4][4];
#pragma unroll
            for (int mi = 0; mi < 4; mi++)
#pragma unroll
                for (int ni = 0; ni < 4; ni++)
                    acc[mi][ni] = bv1[mi];
#pragma unroll
            for (int kt = 0; kt < 8; kt++) {
                s8v wa[4], xb[4];
#pragma unroll
                for (int mi = 0; mi < 4; mi++)
                    wa[mi] = *reinterpret_cast<const s8v*>(Wc1 + ((((4 * fg + mi) * 8 + kt) * 64 + lane) << 3));
#pragma unroll
                for (int ni = 0; ni < 4; ni++)
                    xb[ni] = *reinterpret_cast<const s8v*>(&H1[(((4 * tg + ni) * 8 + kt) * 64 + lane) << 3]);
#pragma unroll
                for (int mi = 0; mi < 4; mi++)
#pragma unroll
                    for (int ni = 0; ni < 4; ni++)
                        acc[mi][ni] = __builtin_amdgcn_mfma_f32_16x16x32_bf16(wa[mi], xb[ni], acc[mi][ni], 0, 0, 0);
            }
#pragma unroll
            for (int mi = 0; mi < 4; mi++) {
                int ft = 4 * fg + mi;
                int kt_h = ft >> 1;
                int lanep = l15 + 16 * ((ft & 1) * 2 + (lq >> 1));
                int j0 = (lq & 1) * 4;
#pragma unroll
                for (int ni = 0; ni < 4; ni++) {
                    int nt = 4 * tg + ni;
                    float t0 = tanh_fast(acc[mi][ni][0]);
                    float t1 = tanh_fast(acc[mi][ni][1]);
                    float t2 = tanh_fast(acc[mi][ni][2]);
                    float t3 = tanh_fast(acc[mi][ni][3]);
                    uint2 pk; pk.x = pk2(t0, t1); pk.y = pk2(t2, t3);
                    *reinterpret_cast<uint2*>(&XH2[(((nt * 8 + kt_h) * 64 + lanep) << 3) + j0]) = pk;
                }
            }
        }
        __syncthreads();

        // ---- Layer 2: O^T = W2^T H2^T. 4 mt x 8 nt / 8 waves = 1 mt x 4 nt per wave.
        {
            f4v acc2[4];
#pragma unroll
            for (int e = 0; e < 4; e++) acc2[e] = bv2;
#pragma unroll
            for (int kt = 0; kt < 8; kt++) {
                s8v wa = *reinterpret_cast<const s8v*>(Wc2 + (((mt2 * 8 + kt) * 64 + lane) << 3));
#pragma unroll
                for (int e = 0; e < 4; e++) {
                    s8v xb = *reinterpret_cast<const s8v*>(&XH2[(((ntb2 + e) * 8 + kt) * 64 + lane) << 3]);
                    acc2[e] = __builtin_amdgcn_mfma_f32_16x16x32_bf16(wa, xb, acc2[e], 0, 0, 0);
                }
            }
#pragma unroll
            for (int e = 0; e < 4; e++) {
                int tok = perm[tile * TILE + (ntb2 + e) * 16 + l15];
                if ((unsigned)tok < (unsigned)N_TOK) {
                    float4 o;
                    o.x = acc2[e][0]; o.y = acc2[e][1]; o.z = acc2[e][2]; o.w = acc2[e][3];
                    *reinterpret_cast<float4*>(out + (size_t)tok * 64 + mt2 * 16 + lq * 4) = o;
                }
            }
        }
        __syncthreads();   // XH2 (H2) reads done -> free for next tile's X stage
    }
}

// ---------------------------------------------------------------- launch
extern "C" void kernel_launch(void* const* d_in, const int* in_sizes, int n_in,
                              void* d_out, int out_size, void* d_ws, size_t ws_size,
                              hipStream_t stream) {
    const float* inputs = (const float*)d_in[0];
    const int*   task   = (const int*)d_in[1];
    const int*   cmap   = (const int*)d_in[2];
    const float* W0     = (const float*)d_in[3];
    const float* b0     = (const float*)d_in[4];
    const float* W1     = (const float*)d_in[5];
    const float* b1     = (const float*)d_in[6];
    const float* W2     = (const float*)d_in[7];
    const float* b2     = (const float*)d_in[8];
    float* out = (float*)d_out;

    char* ws = (char*)d_ws;
    int* blockCounts = (int*)(ws + 0);            // 64*16*4 = 4096 B
    int* tbaseG      = (int*)(ws + 4096);         // 17*4 = 68 B, padded to 128
    int* perm        = (int*)(ws + 4224);         // 1040*128*4 = 532480 B -> ends 536704
    ushort_t* W0p    = (ushort_t*)(ws + 536704);  // 262144 B
    ushort_t* W1p    = (ushort_t*)(ws + 798848);  // 524288 B
    ushort_t* W2p    = (ushort_t*)(ws + 1323136); // 131072 B -> total ~1.45 MB

    prep_hist_kernel<<<288, 256, 0, stream>>>(W0, W1, W2, W0p, W1p, W2p, task, blockCounts);
    sort_kernel<<<64, 256, 0, stream>>>(task, blockCounts, tbaseG, perm);
    mlp_kernel<<<NBLK, 512, 0, stream>>>(inputs, cmap, b0, b1, b2,
                                         W0p, W1p, W2p, tbaseG, perm, out);
}

// Round 11
// 162.511 us; speedup vs baseline: 1.5485x; 1.5485x over previous
//
#include <hip/hip_runtime.h>

#define N_TOK 131072
#define TILE 64              // tokens per tile
#define NT_MAX 2064          // N_TOK/TILE + 16 tasks worth of padding tiles
#define NBLK 256             // 16 tasks x 16 blocks, XCD-mapped: 2 tasks per XCD

typedef __attribute__((ext_vector_type(8))) short s8v;
typedef __attribute__((ext_vector_type(4))) float f4v;
typedef unsigned short ushort_t;

__device__ __forceinline__ unsigned short f2bf(float x) {
    union { float f; unsigned u; } v; v.f = x;
    unsigned r = v.u + 0x7fffu + ((v.u >> 16) & 1u);   // RNE (prep only)
    return (unsigned short)(r >> 16);
}

// round-half-up pack of two f32 -> packed bf16x2 via v_perm_b32 (3 VALU ops)
__device__ __forceinline__ unsigned pk2(float a, float b) {
    union { float f; unsigned u; } x, y; x.f = a; y.f = b;
    return __byte_perm(x.u + 0x8000u, y.u + 0x8000u, 0x7632);
}

// tanh = 1 - 2/(e^2x+1); e^2x = exp2(x * 2*log2(e)): mul, exp2, add, rcp, fma
__device__ __forceinline__ float tanh_fast(float x) {
    float e = __builtin_amdgcn_exp2f(x * 2.8853900817779268f);
    float r = __builtin_amdgcn_rcpf(e + 1.0f);
    return __builtin_fmaf(-2.0f, r, 1.0f);
}

// ------------------------------------------------- fused prep + hist
__global__ void prep_hist_kernel(const float* __restrict__ W0, const float* __restrict__ W1,
                                 const float* __restrict__ W2,
                                 ushort_t* __restrict__ W0p, ushort_t* __restrict__ W1p,
                                 ushort_t* __restrict__ W2p,
                                 const int* __restrict__ task, int* __restrict__ blockCounts) {
    if (blockIdx.x < 224) {
        int f = blockIdx.x * 256 + threadIdx.x;   // 57344 total fragments
        const float* src; ushort_t* dst; int K, N;
        if (f < 16384)      { src = W0; dst = W0p; K = 128; N = 256; }
        else if (f < 49152) { src = W1; dst = W1p; K = 256; N = 256; f -= 16384; }
        else                { src = W2; dst = W2p; K = 256; N = 64;  f -= 49152; }
        int fpc = (N >> 4) * (K >> 5) * 64;       // fragments per copy
        int c = f / fpc, r = f % fpc;
        int lane = r & 63;
        int kt = (r >> 6) % (K >> 5);
        int ftile = (r >> 6) / (K >> 5);
        int n = ftile * 16 + (lane & 15);
        int kbase = kt * 32 + (lane >> 4) * 8;
        const float* s = src + (size_t)c * K * N + (size_t)kbase * N + n;
        s8v pk;
#pragma unroll
        for (int j = 0; j < 8; j++) pk[j] = (short)f2bf(s[(size_t)j * N]);
        *reinterpret_cast<s8v*>(dst + ((size_t)(c * fpc + r) << 3)) = pk;
    } else {
        __shared__ int cnt[16];
        int t = threadIdx.x;
        int hb = blockIdx.x - 224;
        if (t < 16) cnt[t] = 0;
        __syncthreads();
        int base = hb * 2048 + t;
#pragma unroll
        for (int i = 0; i < 8; i++) atomicAdd(&cnt[task[base + i * 256]], 1);
        __syncthreads();
        if (t < 16) blockCounts[hb * 16 + t] = cnt[t];
    }
}

// ------------------------------------------------- fused scan + scatter
// Exports tbase[17] (tile range per task) for the persistent mlp kernel.
__global__ void sort_kernel(const int* __restrict__ task, const int* __restrict__ blockCounts,
                            int* __restrict__ tbaseG, int* __restrict__ perm) {
    __shared__ int cntLds[1024];
    __shared__ int total[16], pref[16], rank[16];
    __shared__ int tokBase[16], tbase[17];
    int t = threadIdx.x, b = blockIdx.x;
    for (int i = t; i < 1024; i += 256) cntLds[i] = blockCounts[i];
    if (t < 16) rank[t] = 0;
    __syncthreads();
    if (t < 16) {
        int tot = 0, pf = 0;
#pragma unroll
        for (int bb = 0; bb < 64; bb++) {
            int v = cntLds[bb * 16 + t];
            tot += v;
            if (bb < b) pf += v;
        }
        total[t] = tot; pref[t] = pf;
    }
    __syncthreads();
    if (t == 0) {
        int tok = 0, tile = 0;
        for (int k = 0; k < 16; k++) {
            tokBase[k] = tok;
            tbase[k] = tile;
            int ntk = (total[k] + TILE - 1) / TILE;
            tok += ntk * TILE;
            tile += ntk;
        }
        tbase[16] = tile;
    }
    __syncthreads();
    if (b == 0) {
        if (t < 17) tbaseG[t] = tbase[t];
        // fill padding slots with -1 (don't rely on ws poison being >= N_TOK)
        for (int i = t; i < 16 * TILE; i += 256) {
            int k = i >> 6, off = i & (TILE - 1);
            int idx = total[k] + off;
            int lim = ((total[k] + TILE - 1) / TILE) * TILE;
            if (idx < lim) perm[tokBase[k] + idx] = -1;
        }
    }
    int tk[8], my[8];
#pragma unroll
    for (int i = 0; i < 8; i++) {
        int idx = b * 2048 + i * 256 + t;
        tk[i] = task[idx];
        my[i] = atomicAdd(&rank[tk[i]], 1);
    }
#pragma unroll
    for (int i = 0; i < 8; i++) {
        int idx = b * 2048 + i * 256 + t;
        perm[tokBase[tk[i]] + pref[tk[i]] + my[i]] = idx;
    }
}

// ------------------------------------------------- persistent MLP, 3-barrier pipeline
// R10 postmortem: allocator hard-caps at 128 arch VGPRs (spills rather than
// exceed), so every register-residency scheme was silently reverted. This
// round restructures PHASES at zero VGPR cost: X gets its own double-buffered
// LDS (2x16KB, separate from H2). The dedicated stage phase disappears, one
// of 4 barriers is removed, and the X-gather for tile+1 is issued at L0-top
// and LDS-written mid-L1 -> its drain hides under ~5K cy of L0+L1 compute
// (previously fully exposed at the stage barrier). Hazards: X[i+1] published
// by B3/B4 before L0[i+1]; H1 WAR covered by B3; H2 WAR covered by B4.
// LDS: X 2x16K + H1 32K + H2 32K = 96KB, 1 block/CU (occupancy proven
// irrelevant 18-72%). XCD map: 2 tasks/XCD (FETCH 36.7->34.6MB, R9).
__launch_bounds__(512, 2)
__global__ void mlp_kernel(const float* __restrict__ x_in,
                           const int* __restrict__ cmap,
                           const float* __restrict__ b0,
                           const float* __restrict__ b1,
                           const float* __restrict__ b2,
                           const ushort_t* __restrict__ W0p,
                           const ushort_t* __restrict__ W1p,
                           const ushort_t* __restrict__ W2p,
                           const int* __restrict__ tbaseG,
                           const int* __restrict__ perm,
                           float* __restrict__ out) {
    __shared__ __align__(16) ushort_t Xb[2][8192];   // 16 KB each: 16 frags
    __shared__ __align__(16) ushort_t H1[16384];     // 32 frags = 32 KB
    __shared__ __align__(16) ushort_t H2[16384];     // 32 frags = 32 KB

    int p = blockIdx.x;
    int x = p & 7, s = p >> 3;            // xcd (HW: blockIdx%8), slot-on-xcd
    int k = 2 * x + (s >> 4), sub = s & 15;
    int tBeg = tbaseG[k], tEnd = tbaseG[k + 1];
    if (tBeg + sub >= tEnd) return;

    int t = threadIdx.x;
    int c0 = cmap[k], c1 = cmap[16 + k], c2 = cmap[32 + k];

    int w = t >> 6;                 // wave 0..7
    int lane = t & 63;
    int l15 = lane & 15, lq = lane >> 4;
    int mt2 = w & 3, ntb2 = (w >> 2) * 2;   // layer-2 tile assignment

    const ushort_t* Wc0 = W0p + (size_t)c0 * 32768;
    const ushort_t* Wc1 = W1p + (size_t)c1 * 65536;
    const ushort_t* Wc2 = W2p + (size_t)c2 * 16384;

    // biases, resident
    f4v bv0[2], bv1[2], bv2;
#pragma unroll
    for (int mi = 0; mi < 2; mi++) {
        bv0[mi] = *reinterpret_cast<const f4v*>(b0 + c0 * 256 + (2 * w + mi) * 16 + lq * 4);
        bv1[mi] = *reinterpret_cast<const f4v*>(b1 + c1 * 256 + (2 * w + mi) * 16 + lq * 4);
    }
    bv2 = *reinterpret_cast<const f4v*>(b2 + c2 * 64 + mt2 * 16 + lq * 4);

    // staging coords: thread owns token r, k-range q*16..q*16+15
    int r = t >> 3, q = t & 7;
    int fragid = (r >> 4) * 4 + (q >> 1);
    int lp0 = (r & 15) + 16 * ((q & 1) * 2);
    const float4* xbase = reinterpret_cast<const float4*>(x_in);

    // ---- prologue: gather tile0, write Xb[0], publish
    int tile = tBeg + sub;
    {
        int ptok = perm[tile * TILE + r];
        float4 v0 = make_float4(0.f, 0.f, 0.f, 0.f), v1 = v0, v2 = v0, v3 = v0;
        if ((unsigned)ptok < (unsigned)N_TOK) {
            const float4* src = xbase + (size_t)ptok * 32 + q * 4;
            v0 = src[0]; v1 = src[1]; v2 = src[2]; v3 = src[3];
        }
        uint4 pk0, pk1;
        pk0.x = pk2(v0.x, v0.y); pk0.y = pk2(v0.z, v0.w);
        pk0.z = pk2(v1.x, v1.y); pk0.w = pk2(v1.z, v1.w);
        pk1.x = pk2(v2.x, v2.y); pk1.y = pk2(v2.z, v2.w);
        pk1.z = pk2(v3.x, v3.y); pk1.w = pk2(v3.z, v3.w);
        *reinterpret_cast<uint4*>(&Xb[0][(fragid * 64 + lp0) << 3]) = pk0;
        *reinterpret_cast<uint4*>(&Xb[0][(fragid * 64 + lp0 + 16) << 3]) = pk1;
    }
    __syncthreads();

    int cur = 0;
    for (; tile < tEnd; tile += 16) {
        int ntile = tile + 16;
        bool hasNext = ntile < tEnd;

        // ---- issue next tile's gather at L0-top: drain hides under L0+L1
        float4 a0 = make_float4(0.f, 0.f, 0.f, 0.f), a1 = a0, a2 = a0, a3 = a0;
        if (hasNext) {
            int ptok = perm[ntile * TILE + r];
            if ((unsigned)ptok < (unsigned)N_TOK) {
                const float4* src = xbase + (size_t)ptok * 32 + q * 4;
                a0 = src[0]; a1 = src[1]; a2 = src[2]; a3 = src[3];
            }
        }

        // ---- Layer 0: H1^T = W0^T X^T. Wave w: ftiles {2w,2w+1} x 4 token tiles.
        {
            f4v acc[2][4];
#pragma unroll
            for (int mi = 0; mi < 2; mi++)
#pragma unroll
                for (int nt = 0; nt < 4; nt++)
                    acc[mi][nt] = bv0[mi];
#pragma unroll
            for (int kt = 0; kt < 4; kt++) {
                s8v wa[2], xb[4];
#pragma unroll
                for (int mi = 0; mi < 2; mi++)
                    wa[mi] = *reinterpret_cast<const s8v*>(Wc0 + ((((2 * w + mi) * 4 + kt) * 64 + lane) << 3));
#pragma unroll
                for (int nt = 0; nt < 4; nt++)
                    xb[nt] = *reinterpret_cast<const s8v*>(&Xb[cur][((nt * 4 + kt) * 64 + lane) << 3]);
#pragma unroll
                for (int mi = 0; mi < 2; mi++)
#pragma unroll
                    for (int nt = 0; nt < 4; nt++)
                        acc[mi][nt] = __builtin_amdgcn_mfma_f32_16x16x32_bf16(wa[mi], xb[nt], acc[mi][nt], 0, 0, 0);
            }
#pragma unroll
            for (int mi = 0; mi < 2; mi++) {
                int ft = 2 * w + mi;
                int kt_h = ft >> 1;
                int lanep = l15 + 16 * ((ft & 1) * 2 + (lq >> 1));
                int j0 = (lq & 1) * 4;
#pragma unroll
                for (int nt = 0; nt < 4; nt++) {
                    float t0 = tanh_fast(acc[mi][nt][0]);
                    float t1 = tanh_fast(acc[mi][nt][1]);
                    float t2 = tanh_fast(acc[mi][nt][2]);
                    float t3 = tanh_fast(acc[mi][nt][3]);
                    uint2 pk; pk.x = pk2(t0, t1); pk.y = pk2(t2, t3);
                    *reinterpret_cast<uint2*>(&H1[(((nt * 8 + kt_h) * 64 + lanep) << 3) + j0]) = pk;
                }
            }
        }
        __syncthreads();   // B2: publish H1

        // ---- Layer 1: H2^T = W1^T H1^T; mid-phase, stage X[tile+16] into Xb[cur^1]
        {
            f4v acc[2][4];
#pragma unroll
            for (int mi = 0; mi < 2; mi++)
#pragma unroll
                for (int nt = 0; nt < 4; nt++)
                    acc[mi][nt] = bv1[mi];
#pragma unroll
            for (int kt = 0; kt < 8; kt++) {
                s8v wa[2], xb[4];
#pragma unroll
                for (int mi = 0; mi < 2; mi++)
                    wa[mi] = *reinterpret_cast<const s8v*>(Wc1 + ((((2 * w + mi) * 8 + kt) * 64 + lane) << 3));
#pragma unroll
                for (int nt = 0; nt < 4; nt++)
                    xb[nt] = *reinterpret_cast<const s8v*>(&H1[((nt * 8 + kt) * 64 + lane) << 3]);
#pragma unroll
                for (int mi = 0; mi < 2; mi++)
#pragma unroll
                    for (int nt = 0; nt < 4; nt++)
                        acc[mi][nt] = __builtin_amdgcn_mfma_f32_16x16x32_bf16(wa[mi], xb[nt], acc[mi][nt], 0, 0, 0);
            }
            // stage next X (gather issued at L0-top; wait hides under the MFMAs above)
            if (hasNext) {
                uint4 pk0, pk1;
                pk0.x = pk2(a0.x, a0.y); pk0.y = pk2(a0.z, a0.w);
                pk0.z = pk2(a1.x, a1.y); pk0.w = pk2(a1.z, a1.w);
                pk1.x = pk2(a2.x, a2.y); pk1.y = pk2(a2.z, a2.w);
                pk1.z = pk2(a3.x, a3.y); pk1.w = pk2(a3.z, a3.w);
                *reinterpret_cast<uint4*>(&Xb[cur ^ 1][(fragid * 64 + lp0) << 3]) = pk0;
                *reinterpret_cast<uint4*>(&Xb[cur ^ 1][(fragid * 64 + lp0 + 16) << 3]) = pk1;
            }
#pragma unroll
            for (int mi = 0; mi < 2; mi++) {
                int ft = 2 * w + mi;
                int kt_h = ft >> 1;
                int lanep = l15 + 16 * ((ft & 1) * 2 + (lq >> 1));
                int j0 = (lq & 1) * 4;
#pragma unroll
                for (int nt = 0; nt < 4; nt++) {
                    float t0 = tanh_fast(acc[mi][nt][0]);
                    float t1 = tanh_fast(acc[mi][nt][1]);
                    float t2 = tanh_fast(acc[mi][nt][2]);
                    float t3 = tanh_fast(acc[mi][nt][3]);
                    uint2 pk; pk.x = pk2(t0, t1); pk.y = pk2(t2, t3);
                    *reinterpret_cast<uint2*>(&H2[(((nt * 8 + kt_h) * 64 + lanep) << 3) + j0]) = pk;
                }
            }
        }
        __syncthreads();   // B3: publish H2 (and X[tile+16])

        // ---- Layer 2: O^T = W2^T H2^T. 4 mt x 4 nt tiles / 8 waves = 2 tiles/wave.
        {
            int tok0 = perm[tile * TILE + ntb2 * 16 + l15];
            int tok1 = perm[tile * TILE + (ntb2 + 1) * 16 + l15];
            f4v acc[2];
            acc[0] = bv2; acc[1] = bv2;
#pragma unroll
            for (int kt = 0; kt < 8; kt++) {
                s8v wa = *reinterpret_cast<const s8v*>(Wc2 + (((mt2 * 8 + kt) * 64 + lane) << 3));
#pragma unroll
                for (int e = 0; e < 2; e++) {
                    s8v xb = *reinterpret_cast<const s8v*>(&H2[(((ntb2 + e) * 8 + kt) * 64 + lane) << 3]);
                    acc[e] = __builtin_amdgcn_mfma_f32_16x16x32_bf16(wa, xb, acc[e], 0, 0, 0);
                }
            }
#pragma unroll
            for (int e = 0; e < 2; e++) {
                int tok = e ? tok1 : tok0;
                if ((unsigned)tok < (unsigned)N_TOK) {
                    float4 o;
                    o.x = acc[e][0]; o.y = acc[e][1]; o.z = acc[e][2]; o.w = acc[e][3];
                    *reinterpret_cast<float4*>(out + (size_t)tok * 64 + mt2 * 16 + lq * 4) = o;
                }
            }
        }
        __syncthreads();   // B4: H2 reads done -> L1[i+1] may overwrite
        cur ^= 1;
    }
}

// ---------------------------------------------------------------- launch
extern "C" void kernel_launch(void* const* d_in, const int* in_sizes, int n_in,
                              void* d_out, int out_size, void* d_ws, size_t ws_size,
                              hipStream_t stream) {
    const float* inputs = (const float*)d_in[0];
    const int*   task   = (const int*)d_in[1];
    const int*   cmap   = (const int*)d_in[2];
    const float* W0     = (const float*)d_in[3];
    const float* b0     = (const float*)d_in[4];
    const float* W1     = (const float*)d_in[5];
    const float* b1     = (const float*)d_in[6];
    const float* W2     = (const float*)d_in[7];
    const float* b2     = (const float*)d_in[8];
    float* out = (float*)d_out;

    char* ws = (char*)d_ws;
    int* blockCounts = (int*)(ws + 0);            // 64*16*4 = 4096 B
    int* tbaseG      = (int*)(ws + 4096);         // 17*4 = 68 B, padded to 128
    int* perm        = (int*)(ws + 4224);         // 2064*64*4 = 528384 B
    ushort_t* W0p    = (ushort_t*)(ws + 532608);  // 262144 B
    ushort_t* W1p    = (ushort_t*)(ws + 794752);  // 524288 B
    ushort_t* W2p    = (ushort_t*)(ws + 1319040); // 131072 B -> total ~1.38 MB

    prep_hist_kernel<<<288, 256, 0, stream>>>(W0, W1, W2, W0p, W1p, W2p, task, blockCounts);
    sort_kernel<<<64, 256, 0, stream>>>(task, blockCounts, tbaseG, perm);
    mlp_kernel<<<NBLK, 512, 0, stream>>>(inputs, cmap, b0, b1, b2,
                                         W0p, W1p, W2p, tbaseG, perm, out);
}